// Round 16
// baseline (1173.160 us; speedup 1.0000x reference)
//
#include <hip/hip_runtime.h>

#define N_NODES 50000
#define IN_DIM  3000
#define HID     512
#define LAT     30
#define N_EDGES 800000
#define M_PAD   50048   // 391*128
#define K1_PAD  3008    // 47*64
#define N4_PAD  3072    // 24*128

typedef __bf16 bf16;
typedef unsigned int uint;
typedef __attribute__((ext_vector_type(4))) float f32x4;
typedef __attribute__((ext_vector_type(8))) bf16 bf16x8;

__device__ __forceinline__ float bf2f(bf16 b){ return (float)b; }

__device__ __forceinline__ void gl16(const void* g, void* l){
  __builtin_amdgcn_global_load_lds(
      (const __attribute__((address_space(1))) void*)g,
      (__attribute__((address_space(3))) void*)l, 16, 0, 0);
}

// bijective XCD-aware swizzle (m204)
__device__ __forceinline__ int xcd_swz(int orig, int nwg){
  int q = nwg >> 3, r = nwg & 7;
  int xcd = orig & 7, lid = orig >> 3;
  return (xcd < r ? xcd*(q+1) : r*(q+1) + (xcd-r)*q) + lid;
}

// ---------------- weight prep (all linear layouts) ----------------
__global__ void k_w1t(const float* __restrict__ W1, bf16* __restrict__ W1T){
  int k = blockIdx.x*256 + threadIdx.x;
  int n = blockIdx.y;
  if (k >= K1_PAD) return;
  float v = (k < IN_DIM) ? W1[(long)k*HID + n] : 0.f;
  W1T[(long)n*K1_PAD + k] = (bf16)v;
}
__global__ void k_w1p(const float* __restrict__ W1, bf16* __restrict__ W1P){
  int k = blockIdx.x*256 + threadIdx.x;
  int n = blockIdx.y;
  if (k >= HID) return;
  float v = (n < IN_DIM) ? W1[(long)n*HID + k] : 0.f;
  W1P[(long)n*HID + k] = (bf16)v;
}
__global__ void k_w2t(const float* __restrict__ W2, bf16* __restrict__ W2T){
  int k = blockIdx.x*256 + threadIdx.x;
  int n = blockIdx.y;
  if (k >= HID) return;
  float v = (n < LAT) ? W2[(long)k*LAT + n] : 0.f;
  W2T[(long)n*HID + k] = (bf16)v;
}
__global__ void k_w2p(const float* __restrict__ W2, bf16* __restrict__ W2P){
  int t = blockIdx.x*256 + threadIdx.x;
  if (t >= HID*32) return;
  int n = t >> 5, k = t & 31;
  W2P[t] = (bf16)((k < LAT) ? W2[(long)n*LAT + k] : 0.f);
}

// ---------------- x fp32 -> xb bf16 [N_NODES rows][K1_PAD] ----------------
// One row per block, 384 threads (376 active). Tail chunk (cols 3000..3007)
// written zero every call (replays leave fp32 junk that can alias NaN bf16).
__global__ __launch_bounds__(384) void k_cvt(const float* __restrict__ x, bf16* __restrict__ xb){
  int chunk = threadIdx.x;
  int row = blockIdx.x;
  if (chunk >= K1_PAD/8) return;
  int c8 = chunk*8;
  bf16x8 o;
  if (c8 + 8 <= IN_DIM){
    float4 v0 = *(const float4*)(x + (long)row*IN_DIM + c8);
    float4 v1 = *(const float4*)(x + (long)row*IN_DIM + c8 + 4);
    o[0]=(bf16)v0.x; o[1]=(bf16)v0.y; o[2]=(bf16)v0.z; o[3]=(bf16)v0.w;
    o[4]=(bf16)v1.x; o[5]=(bf16)v1.y; o[6]=(bf16)v1.z; o[7]=(bf16)v1.w;
  } else {
    #pragma unroll
    for (int j=0;j<8;j++) o[j] = (bf16)0.f;
  }
  *(bf16x8*)(xb + (long)row*K1_PAD + c8) = o;
}

// ---- gemm64: C = A * B^T, 128^2 tile, BK=64, counted-vmcnt 2-phase ----
// Halves the per-K-step fixed overhead (barriers + wait) vs BK=32; 32 MFMA
// per window. 128B bf16 rows would be a 16-way LDS conflict -> chunk-XOR
// swizzle phys = chunk ^ (row&7), applied per-lane on the GLOBAL source
// (linear gl16 dests, rule #21); the 8 permuted 16B chunks cover the same
// 128B segment so coalescing is unchanged. A and B both source-swizzled;
// all global buffers stay linear.
template<bool C_F32>
__global__ __launch_bounds__(256) void gemm64(
    const bf16* __restrict__ A, const bf16* __restrict__ B, void* __restrict__ Cp,
    int lda, int ldb, int Ksteps, int Mvalid, int Nvalid, int ldc, int NBX)
{
  __shared__ bf16 Alds[2][128*64];   // 2 x 16 KB
  __shared__ bf16 Blds[2][128*64];   // 2 x 16 KB
  const int tid  = threadIdx.x;
  const int lane = tid & 63;
  const int w    = tid >> 6;
  const int wm   = (w >> 1) * 64, wn = (w & 1) * 64;
  const int wgid = xcd_swz(blockIdx.x, gridDim.x);
  const int col0 = (wgid % NBX) * 128, row0 = (wgid / NBX) * 128;

  f32x4 acc[4][4];
  #pragma unroll
  for (int mi=0;mi<4;mi++)
    #pragma unroll
    for (int ni=0;ni<4;ni++)
      acc[mi][ni] = (f32x4){0.f,0.f,0.f,0.f};

  // staging: pass i (0..3) covers rows i*32 + (tid>>3); phys chunk tid&7.
  // logical chunk = (tid&7) ^ (row&7); row&7 = (tid>>3)&7 (i*32 == 0 mod 8).
  const int srow  = tid >> 3;
  const int lchB  = ((tid & 7) ^ (srow & 7)) * 8;   // element offset

#define STG64(buf, ks) do{                                              \
    const long ko_ = (long)(ks)*64 + lchB;                              \
    char* la_ = (char*)&Alds[buf][0] + tid*16;                          \
    char* lb_ = (char*)&Blds[buf][0] + tid*16;                         \
    _Pragma("unroll")                                                   \
    for (int i_=0;i_<4;i_++)                                            \
      gl16(A + (long)(row0 + i_*32 + srow)*lda + ko_, la_ + i_*4096);   \
    _Pragma("unroll")                                                   \
    for (int i_=0;i_<4;i_++)                                            \
      gl16(B + (long)(col0 + i_*32 + srow)*ldb + ko_, lb_ + i_*4096);   \
  }while(0)

  STG64(0, 0);

  const int rl = lane & 15;
  const int g  = lane >> 4;

  for (int ks = 0; ks < Ksteps; ks++){
    const int cur = ks & 1;
    if (ks + 1 < Ksteps){
      STG64(cur^1, ks+1);
      asm volatile("s_waitcnt vmcnt(8)" ::: "memory");  // stage(ks) landed
    } else {
      asm volatile("s_waitcnt vmcnt(0)" ::: "memory");
    }
    __builtin_amdgcn_s_barrier();

    const char* Ac = (const char*)&Alds[cur][0];
    const char* Bc = (const char*)&Blds[cur][0];
    #pragma unroll
    for (int ksub=0; ksub<2; ksub++){
      bf16x8 af[4], bfr[4];
      #pragma unroll
      for (int mi=0;mi<4;mi++){
        int r = wm + mi*16 + rl;
        int p = (ksub*4 + g) ^ (r & 7);
        af[mi] = *(const bf16x8*)(Ac + r*128 + p*16);
      }
      #pragma unroll
      for (int ni=0;ni<4;ni++){
        int r = wn + ni*16 + rl;
        int p = (ksub*4 + g) ^ (r & 7);
        bfr[ni] = *(const bf16x8*)(Bc + r*128 + p*16);
      }
      #pragma unroll
      for (int mi=0;mi<4;mi++)
        #pragma unroll
        for (int ni=0;ni<4;ni++)
          acc[mi][ni] = __builtin_amdgcn_mfma_f32_16x16x32_bf16(af[mi], bfr[ni], acc[mi][ni], 0, 0, 0);
    }

    __builtin_amdgcn_s_barrier();
  }
#undef STG64

  const int crb  = (lane >> 4) * 4;
  const int ccol = lane & 15;
  #pragma unroll
  for (int mi=0;mi<4;mi++){
    #pragma unroll
    for (int v=0;v<4;v++){
      int r = row0 + wm + mi*16 + crb + v;
      if (r >= Mvalid) continue;
      #pragma unroll
      for (int ni=0;ni<4;ni++){
        int c = col0 + wn + ni*16 + ccol;
        if (c >= Nvalid) continue;
        float val = acc[mi][ni][v];
        if (C_F32) ((float*)Cp)[(long)r*ldc + c] = val;
        else       ((bf16*)Cp)[(long)r*ldc + c] = (bf16)val;
      }
    }
  }
}

// ---- GEMM: C = A * B^T, 128^2, BK=32 counted-vmcnt dbuf (r8/r13 proven) ----
template<bool C_F32, bool ELU>
__global__ __launch_bounds__(256) void gemm_glds(
    const bf16* __restrict__ A, const bf16* __restrict__ B, void* __restrict__ Cp,
    int lda, int ldb, int Ksteps, int Mvalid, int Nvalid, int ldc, int NBX)
{
  __shared__ bf16 Alds[2][128*32];
  __shared__ bf16 Blds[2][128*32];
  const int tid  = threadIdx.x;
  const int lane = tid & 63;
  const int w    = tid >> 6;
  const int wm   = (w >> 1) * 64, wn = (w & 1) * 64;
  const int wgid = xcd_swz(blockIdx.x, gridDim.x);
  const int col0 = (wgid % NBX) * 128, row0 = (wgid / NBX) * 128;

  f32x4 acc[4][4];
  #pragma unroll
  for (int mi=0;mi<4;mi++)
    #pragma unroll
    for (int ni=0;ni<4;ni++)
      acc[mi][ni] = (f32x4){0.f,0.f,0.f,0.f};

  const int sr = tid >> 2;
  const int sc = (tid & 3) * 16;
  const char* ga = (const char*)(A + (long)(row0 + sr) * lda) + sc;
  const char* gb = (const char*)(B + (long)(col0 + sr) * ldb) + sc;
  const long astep = (long)64 * lda * 2;
  const long bstep = (long)64 * ldb * 2;

#define STAGE_G(buf, ks) do{                                            \
    const long ko_ = (long)(ks) * 64;                                   \
    char* la_ = (char*)&Alds[buf][0] + sr*64 + sc;                      \
    char* lb_ = (char*)&Blds[buf][0] + sr*64 + sc;                      \
    gl16(ga + ko_,         la_);                                        \
    gl16(ga + ko_ + astep, la_ + 64*64);                                \
    gl16(gb + ko_,         lb_);                                        \
    gl16(gb + ko_ + bstep, lb_ + 64*64);                                \
  }while(0)

  STAGE_G(0, 0);

  for (int ks = 0; ks < Ksteps; ks++){
    const int cur = ks & 1;
    if (ks + 1 < Ksteps){
      STAGE_G(cur^1, ks+1);
      asm volatile("s_waitcnt vmcnt(4)" ::: "memory");
    } else {
      asm volatile("s_waitcnt vmcnt(0)" ::: "memory");
    }
    __builtin_amdgcn_s_barrier();

    const bf16* Ac = &Alds[cur][0];
    const bf16* Bc = &Blds[cur][0];
    bf16x8 af[4], bfr[4];
    #pragma unroll
    for (int mi=0;mi<4;mi++)
      af[mi] = *(const bf16x8*)&Ac[(wm + mi*16 + (lane & 15))*32 + (lane>>4)*8];
    #pragma unroll
    for (int ni=0;ni<4;ni++)
      bfr[ni] = *(const bf16x8*)&Bc[(wn + ni*16 + (lane & 15))*32 + (lane>>4)*8];
    #pragma unroll
    for (int mi=0;mi<4;mi++)
      #pragma unroll
      for (int ni=0;ni<4;ni++)
        acc[mi][ni] = __builtin_amdgcn_mfma_f32_16x16x32_bf16(af[mi], bfr[ni], acc[mi][ni], 0, 0, 0);

    __builtin_amdgcn_s_barrier();
  }
#undef STAGE_G

  const int crb  = (lane >> 4) * 4;
  const int ccol = lane & 15;
  #pragma unroll
  for (int mi=0;mi<4;mi++){
    #pragma unroll
    for (int v=0;v<4;v++){
      int r = row0 + wm + mi*16 + crb + v;
      if (r >= Mvalid) continue;
      #pragma unroll
      for (int ni=0;ni<4;ni++){
        int c = col0 + wn + ni*16 + ccol;
        if (c >= Nvalid) continue;
        float val = acc[mi][ni][v];
        if (ELU) val = (val > 0.f) ? val : expm1f(val);
        if (C_F32) ((float*)Cp)[(long)r*ldc + c] = val;
        else       ((bf16*)Cp)[(long)r*ldc + c] = (bf16)val;
      }
    }
  }
}

// ---------------- attention dots ----------------
__global__ void k_attdots(const bf16* __restrict__ h1, const float* __restrict__ att_s,
                          const float* __restrict__ att_d, float* __restrict__ a_src,
                          float* __restrict__ a_dst){
  int gid = blockIdx.x * blockDim.x + threadIdx.x;
  int row = gid >> 6, lane = gid & 63;
  if (row >= N_NODES) return;
  bf16x8 hv = *(const bf16x8*)(h1 + (long)row*HID + lane*8);
  float s1 = 0.f, s2 = 0.f;
  #pragma unroll
  for (int j=0;j<8;j++){
    float h = bf2f(hv[j]);
    s1 = fmaf(h, att_s[lane*8+j], s1);
    s2 = fmaf(h, att_d[lane*8+j], s2);
  }
  #pragma unroll
  for (int o=32;o>0;o>>=1){ s1 += __shfl_down(s1,o); s2 += __shfl_down(s2,o); }
  if (lane == 0){ a_src[row] = s1; a_dst[row] = s2; }
}

// ---------------- CSR build ----------------
__global__ void k_deg(const int* __restrict__ ei, int* __restrict__ deg){
  int e = blockIdx.x*256 + threadIdx.x;
  if (e >= N_EDGES) return;
  atomicAdd(&deg[ei[N_EDGES + e]], 1);
}

__global__ void k_scan(const int* __restrict__ deg, int* __restrict__ off, int* __restrict__ cur){
  const int n = M_PAD, T = 1024;
  int t = threadIdx.x;
  const int per = (n + T - 1) / T;
  int s0 = t*per, s1 = min(n, s0+per);
  int sum = 0;
  for (int i=s0;i<s1;i++) sum += deg[i];
  __shared__ int sd[1024];
  sd[t] = sum; __syncthreads();
  for (int o=1;o<T;o<<=1){
    int x = (t>=o) ? sd[t-o] : 0;
    __syncthreads();
    sd[t] += x;
    __syncthreads();
  }
  int run = sd[t] - sum;
  for (int i=s0;i<s1;i++){
    off[i] = run; cur[i] = run;
    run += deg[i];
  }
  if (s0 < n && s1 == n) off[n] = run;
}

// fill CSR and compute unnormalized p = exp(leaky(a_src+a_dst)) per slot.
__global__ void k_fill(const int* __restrict__ ei, int* __restrict__ cur,
                       int* __restrict__ csr_src, const float* __restrict__ a_s,
                       const float* __restrict__ a_d, float* __restrict__ p_e){
  int e = blockIdx.x*256 + threadIdx.x;
  if (e >= N_EDGES) return;
  int s = ei[e];
  int d = ei[N_EDGES + e];
  int pos = atomicAdd(&cur[d], 1);
  csr_src[pos] = s;
  float v = a_s[s] + a_d[d];
  v = (v > 0.f) ? v : 0.2f*v;
  p_e[pos] = __expf(v);
}

// -------- conv1 aggregation: wave per node, bf16x8 loads, 2-edge unroll ----
__global__ __launch_bounds__(256) void k_agg1w(
    const int* __restrict__ off, const int* __restrict__ csr_src,
    const float* __restrict__ p_edge,
    const bf16* __restrict__ h1, bf16* __restrict__ x1,
    float* __restrict__ s_node)
{
  const int i = blockIdx.x*4 + (threadIdx.x >> 6);
  const int lane = threadIdx.x & 63;
  if (i >= N_NODES) return;
  const int start = off[i];
  const int deg = off[i+1] - start;

  float acc[8];
  #pragma unroll
  for (int j=0;j<8;j++) acc[j] = 0.f;
  float ssum = 0.f;

  int k = 0;
  for (; k+1 < deg; k += 2){
    int s0 = csr_src[start+k],   s1 = csr_src[start+k+1];
    float p0 = p_edge[start+k],  p1 = p_edge[start+k+1];
    ssum += p0 + p1;
    bf16x8 h0 = *(const bf16x8*)(h1 + (long)s0*HID + lane*8);
    bf16x8 hv1 = *(const bf16x8*)(h1 + (long)s1*HID + lane*8);
    #pragma unroll
    for (int j=0;j<8;j++){
      acc[j] = fmaf(p0, bf2f(h0[j]), acc[j]);
      acc[j] = fmaf(p1, bf2f(hv1[j]), acc[j]);
    }
  }
  if (k < deg){
    int s = csr_src[start+k];
    float pk = p_edge[start+k];
    ssum += pk;
    bf16x8 hv = *(const bf16x8*)(h1 + (long)s*HID + lane*8);
    #pragma unroll
    for (int j=0;j<8;j++) acc[j] = fmaf(pk, bf2f(hv[j]), acc[j]);
  }
  float inv = 1.f/(ssum + 1e-16f);
  bf16x8 o;
  #pragma unroll
  for (int j=0;j<8;j++){
    float v = acc[j]*inv;
    v = (v > 0.f) ? v : expm1f(v);
    o[j] = (bf16)v;
  }
  *(bf16x8*)(x1 + (long)i*HID + lane*8) = o;
  if (lane == 0) s_node[i] = ssum;
}

// ---------------- conv3 aggregate ----------------
__global__ void k_agg3(const int* __restrict__ off, const int* __restrict__ csr_src,
                       const float* __restrict__ p_edge, const float* __restrict__ s_node,
                       const float* __restrict__ x2, bf16* __restrict__ aggb)
{
  int i = blockIdx.x*8 + (threadIdx.x >> 5);
  int lane = threadIdx.x & 31;
  if (i >= M_PAD) return;
  float acc = 0.f;
  if (i < N_NODES){
    int s0 = off[i], d = off[i+1] - s0;
    for (int k=0;k<d;k++){
      int s = csr_src[s0+k];
      float pk = p_edge[s0+k];
      if (lane < LAT) acc = fmaf(pk, x2[(long)s*LAT + lane], acc);
    }
    acc *= 1.f/(s_node[i] + 1e-16f);
  }
  aggb[(long)i*32 + lane] = (bf16)((lane < LAT) ? acc : 0.f);
}

// ---------------- launch ----------------
extern "C" void kernel_launch(void* const* d_in, const int* in_sizes, int n_in,
                              void* d_out, int out_size, void* d_ws, size_t ws_size,
                              hipStream_t stream)
{
  const float* x     = (const float*)d_in[0];
  const int*   ei    = (const int*)d_in[1];
  const float* W1    = (const float*)d_in[2];
  const float* W2    = (const float*)d_in[3];
  const float* att_s = (const float*)d_in[4];
  const float* att_d = (const float*)d_in[5];

  float* out_x2 = (float*)d_out;                        // [N,30]
  float* out_x4 = (float*)d_out + (long)N_NODES*LAT;    // [N,3000] region (600 MB)

  // transient scratch in the (not-yet-written) x4 region of d_out
  bf16* xb = (bf16*)out_x4;                             // [M_PAD][K1_PAD] 301 MB
  bf16* h1 = xb + (long)M_PAD*K1_PAD;                   // [M_PAD][HID]
  bf16* x1 = h1 + (long)M_PAD*HID;                      // [M_PAD][HID]

  char* w = (char*)d_ws;
  bf16* W1T = (bf16*)w;  w += (long)HID*K1_PAD*2;
  bf16* W1P = (bf16*)w;  w += (long)N4_PAD*HID*2;
  bf16* W2T = (bf16*)w;  w += (long)128*HID*2;
  bf16* W2P = (bf16*)w;  w += (long)HID*32*2;
  bf16* x3  = (bf16*)w;  w += (long)M_PAD*HID*2;
  bf16* aggb= (bf16*)w;  w += (long)M_PAD*32*2;
  int* deg  = (int*)w;   w += (long)M_PAD*4;
  int* offs = (int*)w;   w += (long)(M_PAD+64)*4;
  int* cur  = (int*)w;   w += (long)M_PAD*4;
  int* csr  = (int*)w;   w += (long)N_EDGES*4;
  float* p_e = (float*)w; w += (long)N_EDGES*4;
  float* s_n = (float*)w; w += (long)M_PAD*4;
  float* a_s = (float*)w; w += (long)M_PAD*4;
  float* a_d = (float*)w; w += (long)M_PAD*4;

  // weight prep + input convert
  k_w1t<<<dim3((K1_PAD+255)/256, HID), 256, 0, stream>>>(W1, W1T);
  k_w1p<<<dim3((HID+255)/256, N4_PAD), 256, 0, stream>>>(W1, W1P);
  k_w2t<<<dim3(2, 128), 256, 0, stream>>>(W2, W2T);
  k_w2p<<<(HID*32+255)/256, 256, 0, stream>>>(W2, W2P);
  k_cvt<<<N_NODES, 384, 0, stream>>>(x, xb);

  // CSR degree + offsets
  hipMemsetAsync(deg, 0, (size_t)M_PAD*4, stream);
  k_deg<<<(N_EDGES+255)/256, 256, 0, stream>>>(ei, deg);
  k_scan<<<1, 1024, 0, stream>>>(deg, offs, cur);

  // h1 = xb @ W1T^T  [M][512] bf16  (BK=64 counted-vmcnt GEMM, 47 steps)
  gemm64<false><<<(HID/128)*(M_PAD/128), 256, 0, stream>>>(
      xb, W1T, h1, K1_PAD, K1_PAD, K1_PAD/64, N_NODES, HID, HID, HID/128);

  k_attdots<<<(N_NODES*64)/256, 256, 0, stream>>>(h1, att_s, att_d, a_s, a_d);

  // CSR fill + fused edge softmax numerator
  k_fill<<<(N_EDGES+255)/256, 256, 0, stream>>>(ei, cur, csr, a_s, a_d, p_e);

  k_agg1w<<<(N_NODES+3)/4, 256, 0, stream>>>(offs, csr, p_e, h1, x1, s_n);

  // x2 = x1 @ W2 -> fp32 out
  gemm_glds<true,false><<<1*(M_PAD/128), 256, 0, stream>>>(
      x1, W2T, out_x2, HID, HID, HID/32, N_NODES, LAT, LAT, 1);

  // conv3: aggregate on 30-wide x2, then x3 = elu(aggb @ W2P^T)
  k_agg3<<<(M_PAD+7)/8, 256, 0, stream>>>(offs, csr, p_e, s_n, out_x2, aggb);
  gemm_glds<false,true><<<(HID/128)*(M_PAD/128), 256, 0, stream>>>(
      aggb, W2P, x3, 32, 32, 1, M_PAD, HID, HID, HID/128);

  // x4 = x3 @ W1^T -> fp32 out (BK=64, 8 steps; overwrites xb/h1/x1 scratch)
  gemm64<true><<<(N4_PAD/128)*(M_PAD/128), 256, 0, stream>>>(
      x3, W1P, out_x4, HID, HID, HID/64, N_NODES, IN_DIM, IN_DIM, N4_PAD/128);
}

// Round 17
// 1138.471 us; speedup vs baseline: 1.0305x; 1.0305x over previous
//
#include <hip/hip_runtime.h>

#define N_NODES 50000
#define IN_DIM  3000
#define HID     512
#define LAT     30
#define N_EDGES 800000
#define M_PAD   50048   // 391*128
#define K1_PAD  3008    // 94*32
#define N4_PAD  3072    // 24*128

typedef __bf16 bf16;
typedef unsigned int uint;
typedef __attribute__((ext_vector_type(4))) float f32x4;
typedef __attribute__((ext_vector_type(8))) bf16 bf16x8;

__device__ __forceinline__ float bf2f(bf16 b){ return (float)b; }

__device__ __forceinline__ void gl16(const void* g, void* l){
  __builtin_amdgcn_global_load_lds(
      (const __attribute__((address_space(1))) void*)g,
      (__attribute__((address_space(3))) void*)l, 16, 0, 0);
}

// bijective XCD-aware swizzle (m204)
__device__ __forceinline__ int xcd_swz(int orig, int nwg){
  int q = nwg >> 3, r = nwg & 7;
  int xcd = orig & 7, lid = orig >> 3;
  return (xcd < r ? xcd*(q+1) : r*(q+1) + (xcd-r)*q) + lid;
}

// ---------------- weight prep (all linear layouts) ----------------
__global__ void k_w1t(const float* __restrict__ W1, bf16* __restrict__ W1T){
  int k = blockIdx.x*256 + threadIdx.x;
  int n = blockIdx.y;
  if (k >= K1_PAD) return;
  float v = (k < IN_DIM) ? W1[(long)k*HID + n] : 0.f;
  W1T[(long)n*K1_PAD + k] = (bf16)v;
}
__global__ void k_w1p(const float* __restrict__ W1, bf16* __restrict__ W1P){
  int k = blockIdx.x*256 + threadIdx.x;
  int n = blockIdx.y;
  if (k >= HID) return;
  float v = (n < IN_DIM) ? W1[(long)n*HID + k] : 0.f;
  W1P[(long)n*HID + k] = (bf16)v;
}
__global__ void k_w2t(const float* __restrict__ W2, bf16* __restrict__ W2T){
  int k = blockIdx.x*256 + threadIdx.x;
  int n = blockIdx.y;
  if (k >= HID) return;
  float v = (n < LAT) ? W2[(long)k*LAT + n] : 0.f;
  W2T[(long)n*HID + k] = (bf16)v;
}
__global__ void k_w2p(const float* __restrict__ W2, bf16* __restrict__ W2P){
  int t = blockIdx.x*256 + threadIdx.x;
  if (t >= HID*32) return;
  int n = t >> 5, k = t & 31;
  W2P[t] = (bf16)((k < LAT) ? W2[(long)n*LAT + k] : 0.f);
}

// ---------------- x fp32 -> xb bf16 [N_NODES rows][K1_PAD] ----------------
// One row per block, 384 threads (376 active). Tail chunk (cols 3000..3007)
// written zero every call (replays leave fp32 junk that can alias NaN bf16).
__global__ __launch_bounds__(384) void k_cvt(const float* __restrict__ x, bf16* __restrict__ xb){
  int chunk = threadIdx.x;
  int row = blockIdx.x;
  if (chunk >= K1_PAD/8) return;
  int c8 = chunk*8;
  bf16x8 o;
  if (c8 + 8 <= IN_DIM){
    float4 v0 = *(const float4*)(x + (long)row*IN_DIM + c8);
    float4 v1 = *(const float4*)(x + (long)row*IN_DIM + c8 + 4);
    o[0]=(bf16)v0.x; o[1]=(bf16)v0.y; o[2]=(bf16)v0.z; o[3]=(bf16)v0.w;
    o[4]=(bf16)v1.x; o[5]=(bf16)v1.y; o[6]=(bf16)v1.z; o[7]=(bf16)v1.w;
  } else {
    #pragma unroll
    for (int j=0;j<8;j++) o[j] = (bf16)0.f;
  }
  *(bf16x8*)(xb + (long)row*K1_PAD + c8) = o;
}

// ---- GEMM: C = A * B^T, 128^2, counted-vmcnt double-buffer (r8 proven) ----
template<bool C_F32, bool ELU>
__global__ __launch_bounds__(256) void gemm_glds(
    const bf16* __restrict__ A, const bf16* __restrict__ B, void* __restrict__ Cp,
    int lda, int ldb, int Ksteps, int Mvalid, int Nvalid, int ldc, int NBX)
{
  __shared__ bf16 Alds[2][128*32];
  __shared__ bf16 Blds[2][128*32];
  const int tid  = threadIdx.x;
  const int lane = tid & 63;
  const int w    = tid >> 6;
  const int wm   = (w >> 1) * 64, wn = (w & 1) * 64;
  const int wgid = xcd_swz(blockIdx.x, gridDim.x);
  const int col0 = (wgid % NBX) * 128, row0 = (wgid / NBX) * 128;

  f32x4 acc[4][4];
  #pragma unroll
  for (int mi=0;mi<4;mi++)
    #pragma unroll
    for (int ni=0;ni<4;ni++)
      acc[mi][ni] = (f32x4){0.f,0.f,0.f,0.f};

  const int sr = tid >> 2;
  const int sc = (tid & 3) * 16;
  const char* ga = (const char*)(A + (long)(row0 + sr) * lda) + sc;
  const char* gb = (const char*)(B + (long)(col0 + sr) * ldb) + sc;
  const long astep = (long)64 * lda * 2;
  const long bstep = (long)64 * ldb * 2;

#define STAGE_G(buf, ks) do{                                            \
    const long ko_ = (long)(ks) * 64;                                   \
    char* la_ = (char*)&Alds[buf][0] + sr*64 + sc;                      \
    char* lb_ = (char*)&Blds[buf][0] + sr*64 + sc;                      \
    gl16(ga + ko_,         la_);                                        \
    gl16(ga + ko_ + astep, la_ + 64*64);                                \
    gl16(gb + ko_,         lb_);                                        \
    gl16(gb + ko_ + bstep, lb_ + 64*64);                                \
  }while(0)

  STAGE_G(0, 0);

  for (int ks = 0; ks < Ksteps; ks++){
    const int cur = ks & 1;
    if (ks + 1 < Ksteps){
      STAGE_G(cur^1, ks+1);
      asm volatile("s_waitcnt vmcnt(4)" ::: "memory");  // stage(ks) landed
    } else {
      asm volatile("s_waitcnt vmcnt(0)" ::: "memory");
    }
    __builtin_amdgcn_s_barrier();                       // all waves' stage done

    const bf16* Ac = &Alds[cur][0];
    const bf16* Bc = &Blds[cur][0];
    bf16x8 af[4], bfr[4];
    #pragma unroll
    for (int mi=0;mi<4;mi++)
      af[mi] = *(const bf16x8*)&Ac[(wm + mi*16 + (lane & 15))*32 + (lane>>4)*8];
    #pragma unroll
    for (int ni=0;ni<4;ni++)
      bfr[ni] = *(const bf16x8*)&Bc[(wn + ni*16 + (lane & 15))*32 + (lane>>4)*8];
    #pragma unroll
    for (int mi=0;mi<4;mi++)
      #pragma unroll
      for (int ni=0;ni<4;ni++)
        acc[mi][ni] = __builtin_amdgcn_mfma_f32_16x16x32_bf16(af[mi], bfr[ni], acc[mi][ni], 0, 0, 0);

    __builtin_amdgcn_s_barrier();                       // reads done before overwrite
  }
#undef STAGE_G

  const int crb  = (lane >> 4) * 4;
  const int ccol = lane & 15;
  #pragma unroll
  for (int mi=0;mi<4;mi++){
    #pragma unroll
    for (int v=0;v<4;v++){
      int r = row0 + wm + mi*16 + crb + v;
      if (r >= Mvalid) continue;
      #pragma unroll
      for (int ni=0;ni<4;ni++){
        int c = col0 + wn + ni*16 + ccol;
        if (c >= Nvalid) continue;
        float val = acc[mi][ni][v];
        if (ELU) val = (val > 0.f) ? val : expm1f(val);
        if (C_F32) ((float*)Cp)[(long)r*ldc + c] = val;
        else       ((bf16*)Cp)[(long)r*ldc + c] = (bf16)val;
      }
    }
  }
}

// ---------------- attention dots ----------------
__global__ void k_attdots(const bf16* __restrict__ h1, const float* __restrict__ att_s,
                          const float* __restrict__ att_d, float* __restrict__ a_src,
                          float* __restrict__ a_dst){
  int gid = blockIdx.x * blockDim.x + threadIdx.x;
  int row = gid >> 6, lane = gid & 63;
  if (row >= N_NODES) return;
  bf16x8 hv = *(const bf16x8*)(h1 + (long)row*HID + lane*8);
  float s1 = 0.f, s2 = 0.f;
  #pragma unroll
  for (int j=0;j<8;j++){
    float h = bf2f(hv[j]);
    s1 = fmaf(h, att_s[lane*8+j], s1);
    s2 = fmaf(h, att_d[lane*8+j], s2);
  }
  #pragma unroll
  for (int o=32;o>0;o>>=1){ s1 += __shfl_down(s1,o); s2 += __shfl_down(s2,o); }
  if (lane == 0){ a_src[row] = s1; a_dst[row] = s2; }
}

// ---------------- CSR build ----------------
__global__ void k_deg(const int* __restrict__ ei, int* __restrict__ deg){
  int e = blockIdx.x*256 + threadIdx.x;
  if (e >= N_EDGES) return;
  atomicAdd(&deg[ei[N_EDGES + e]], 1);
}

__global__ void k_scan(const int* __restrict__ deg, int* __restrict__ off, int* __restrict__ cur){
  const int n = M_PAD, T = 1024;
  int t = threadIdx.x;
  const int per = (n + T - 1) / T;
  int s0 = t*per, s1 = min(n, s0+per);
  int sum = 0;
  for (int i=s0;i<s1;i++) sum += deg[i];
  __shared__ int sd[1024];
  sd[t] = sum; __syncthreads();
  for (int o=1;o<T;o<<=1){
    int x = (t>=o) ? sd[t-o] : 0;
    __syncthreads();
    sd[t] += x;
    __syncthreads();
  }
  int run = sd[t] - sum;
  for (int i=s0;i<s1;i++){
    off[i] = run; cur[i] = run;
    run += deg[i];
  }
  if (s0 < n && s1 == n) off[n] = run;
}

// fill CSR and compute unnormalized p = exp(leaky(a_src+a_dst)) per slot.
__global__ void k_fill(const int* __restrict__ ei, int* __restrict__ cur,
                       int* __restrict__ csr_src, const float* __restrict__ a_s,
                       const float* __restrict__ a_d, float* __restrict__ p_e){
  int e = blockIdx.x*256 + threadIdx.x;
  if (e >= N_EDGES) return;
  int s = ei[e];
  int d = ei[N_EDGES + e];
  int pos = atomicAdd(&cur[d], 1);
  csr_src[pos] = s;
  float v = a_s[s] + a_d[d];
  v = (v > 0.f) ? v : 0.2f*v;
  p_e[pos] = __expf(v);
}

// -------- conv1 aggregation: wave per node, bf16x8 loads, 2-edge unroll ----
__global__ __launch_bounds__(256) void k_agg1w(
    const int* __restrict__ off, const int* __restrict__ csr_src,
    const float* __restrict__ p_edge,
    const bf16* __restrict__ h1, bf16* __restrict__ x1,
    float* __restrict__ s_node)
{
  const int i = blockIdx.x*4 + (threadIdx.x >> 6);
  const int lane = threadIdx.x & 63;
  if (i >= N_NODES) return;
  const int start = off[i];
  const int deg = off[i+1] - start;

  float acc[8];
  #pragma unroll
  for (int j=0;j<8;j++) acc[j] = 0.f;
  float ssum = 0.f;

  int k = 0;
  for (; k+1 < deg; k += 2){
    int s0 = csr_src[start+k],   s1 = csr_src[start+k+1];
    float p0 = p_edge[start+k],  p1 = p_edge[start+k+1];
    ssum += p0 + p1;
    bf16x8 h0 = *(const bf16x8*)(h1 + (long)s0*HID + lane*8);
    bf16x8 hv1 = *(const bf16x8*)(h1 + (long)s1*HID + lane*8);
    #pragma unroll
    for (int j=0;j<8;j++){
      acc[j] = fmaf(p0, bf2f(h0[j]), acc[j]);
      acc[j] = fmaf(p1, bf2f(hv1[j]), acc[j]);
    }
  }
  if (k < deg){
    int s = csr_src[start+k];
    float pk = p_edge[start+k];
    ssum += pk;
    bf16x8 hv = *(const bf16x8*)(h1 + (long)s*HID + lane*8);
    #pragma unroll
    for (int j=0;j<8;j++) acc[j] = fmaf(pk, bf2f(hv[j]), acc[j]);
  }
  float inv = 1.f/(ssum + 1e-16f);
  bf16x8 o;
  #pragma unroll
  for (int j=0;j<8;j++){
    float v = acc[j]*inv;
    v = (v > 0.f) ? v : expm1f(v);
    o[j] = (bf16)v;
  }
  *(bf16x8*)(x1 + (long)i*HID + lane*8) = o;
  if (lane == 0) s_node[i] = ssum;
}

// ---------------- conv3 aggregate ----------------
__global__ void k_agg3(const int* __restrict__ off, const int* __restrict__ csr_src,
                       const float* __restrict__ p_edge, const float* __restrict__ s_node,
                       const float* __restrict__ x2, bf16* __restrict__ aggb)
{
  int i = blockIdx.x*8 + (threadIdx.x >> 5);
  int lane = threadIdx.x & 31;
  if (i >= M_PAD) return;
  float acc = 0.f;
  if (i < N_NODES){
    int s0 = off[i], d = off[i+1] - s0;
    for (int k=0;k<d;k++){
      int s = csr_src[s0+k];
      float pk = p_edge[s0+k];
      if (lane < LAT) acc = fmaf(pk, x2[(long)s*LAT + lane], acc);
    }
    acc *= 1.f/(s_node[i] + 1e-16f);
  }
  aggb[(long)i*32 + lane] = (bf16)((lane < LAT) ? acc : 0.f);
}

// ---------------- launch ----------------
extern "C" void kernel_launch(void* const* d_in, const int* in_sizes, int n_in,
                              void* d_out, int out_size, void* d_ws, size_t ws_size,
                              hipStream_t stream)
{
  const float* x     = (const float*)d_in[0];
  const int*   ei    = (const int*)d_in[1];
  const float* W1    = (const float*)d_in[2];
  const float* W2    = (const float*)d_in[3];
  const float* att_s = (const float*)d_in[4];
  const float* att_d = (const float*)d_in[5];

  float* out_x2 = (float*)d_out;                        // [N,30]
  float* out_x4 = (float*)d_out + (long)N_NODES*LAT;    // [N,3000] region (600 MB)

  // transient scratch in the (not-yet-written) x4 region of d_out
  bf16* xb = (bf16*)out_x4;                             // [M_PAD][K1_PAD] 301 MB
  bf16* h1 = xb + (long)M_PAD*K1_PAD;                   // [M_PAD][HID]
  bf16* x1 = h1 + (long)M_PAD*HID;                      // [M_PAD][HID]

  char* w = (char*)d_ws;
  bf16* W1T = (bf16*)w;  w += (long)HID*K1_PAD*2;
  bf16* W1P = (bf16*)w;  w += (long)N4_PAD*HID*2;
  bf16* W2T = (bf16*)w;  w += (long)128*HID*2;
  bf16* W2P = (bf16*)w;  w += (long)HID*32*2;
  bf16* x3  = (bf16*)w;  w += (long)M_PAD*HID*2;
  bf16* aggb= (bf16*)w;  w += (long)M_PAD*32*2;
  int* deg  = (int*)w;   w += (long)M_PAD*4;
  int* offs = (int*)w;   w += (long)(M_PAD+64)*4;
  int* cur  = (int*)w;   w += (long)M_PAD*4;
  int* csr  = (int*)w;   w += (long)N_EDGES*4;
  float* p_e = (float*)w; w += (long)N_EDGES*4;
  float* s_n = (float*)w; w += (long)M_PAD*4;
  float* a_s = (float*)w; w += (long)M_PAD*4;
  float* a_d = (float*)w; w += (long)M_PAD*4;

  // weight prep + input convert
  k_w1t<<<dim3((K1_PAD+255)/256, HID), 256, 0, stream>>>(W1, W1T);
  k_w1p<<<dim3((HID+255)/256, N4_PAD), 256, 0, stream>>>(W1, W1P);
  k_w2t<<<dim3(2, 128), 256, 0, stream>>>(W2, W2T);
  k_w2p<<<(HID*32+255)/256, 256, 0, stream>>>(W2, W2P);
  k_cvt<<<N_NODES, 384, 0, stream>>>(x, xb);

  // CSR degree + offsets
  hipMemsetAsync(deg, 0, (size_t)M_PAD*4, stream);
  k_deg<<<(N_EDGES+255)/256, 256, 0, stream>>>(ei, deg);
  k_scan<<<1, 1024, 0, stream>>>(deg, offs, cur);

  // h1 = xb @ W1T^T  [M][512] bf16
  gemm_glds<false,false><<<(HID/128)*(M_PAD/128), 256, 0, stream>>>(
      xb, W1T, h1, K1_PAD, K1_PAD, K1_PAD/32, N_NODES, HID, HID, HID/128);

  k_attdots<<<(N_NODES*64)/256, 256, 0, stream>>>(h1, att_s, att_d, a_s, a_d);

  // CSR fill + fused edge softmax numerator
  k_fill<<<(N_EDGES+255)/256, 256, 0, stream>>>(ei, cur, csr, a_s, a_d, p_e);

  k_agg1w<<<(N_NODES+3)/4, 256, 0, stream>>>(offs, csr, p_e, h1, x1, s_n);

  // x2 = x1 @ W2 -> fp32 out
  gemm_glds<true,false><<<1*(M_PAD/128), 256, 0, stream>>>(
      x1, W2T, out_x2, HID, HID, HID/32, N_NODES, LAT, LAT, 1);

  // conv3: aggregate on 30-wide x2, then x3 = elu(aggb @ W2P^T)
  k_agg3<<<(M_PAD+7)/8, 256, 0, stream>>>(offs, csr, p_e, s_n, out_x2, aggb);
  gemm_glds<false,true><<<(HID/128)*(M_PAD/128), 256, 0, stream>>>(
      aggb, W2P, x3, 32, 32, 1, M_PAD, HID, HID, HID/128);

  // x4 = x3 @ W1^T -> fp32 out (overwrites xb/h1/x1 scratch)
  gemm_glds<true,false><<<(N4_PAD/128)*(M_PAD/128), 256, 0, stream>>>(
      x3, W1P, out_x4, HID, HID, HID/32, N_NODES, IN_DIM, IN_DIM, N4_PAD/128);
}